// Round 2
// baseline (1060.329 us; speedup 1.0000x reference)
//
#include <hip/hip_runtime.h>

typedef __attribute__((ext_vector_type(8))) short short8;
typedef __attribute__((ext_vector_type(4))) float f32x4;

#define MFMA16(a, b, c) __builtin_amdgcn_mfma_f32_16x16x32_bf16((a), (b), (c), 0, 0, 0)

// fp32 -> bf16 (round-nearest-even), bit-level (no header type dependence)
static __device__ inline unsigned short f2bf(float f) {
    unsigned int u = __float_as_uint(f);
    u += 0x7fffu + ((u >> 16) & 1u);
    return (unsigned short)(u >> 16);
}

static __device__ inline ushort4 pack4(float4 x) {
    ushort4 r;
    r.x = f2bf(x.x); r.y = f2bf(x.y); r.z = f2bf(x.z); r.w = f2bf(x.w);
    return r;
}

static __device__ inline short8 cvt8(const float* __restrict__ p) {
    float4 x = *(const float4*)p;
    float4 y = *(const float4*)(p + 4);
    short8 r;
    r[0] = (short)f2bf(x.x); r[1] = (short)f2bf(x.y); r[2] = (short)f2bf(x.z); r[3] = (short)f2bf(x.w);
    r[4] = (short)f2bf(y.x); r[5] = (short)f2bf(y.y); r[6] = (short)f2bf(y.z); r[7] = (short)f2bf(y.w);
    return r;
}

// ---------------------------------------------------------------------------
// Kernel 1: QKV projections. Y[m][n] = sum_k X[m][k] * W[n][k] + bias[n]
// M=8192, N=1024, K=1024, three GEMMs selected by blockIdx.z.
// Output: z=0 -> Qh (B,H,T,D) bf16 ; z=1 -> Kh (B,H,T,D) ; z=2 -> Vt (B,H,D,T)
// LDS rows padded to 40 ushorts (80 B = 20 dwords): fragment-read rows 0..7
// hit banks {0,20,8,28,16,4,24,12} -> worst 2-way aliasing (free, m136), and
// 80 % 16 == 0 keeps ds_read_b128 16B-aligned.
// ---------------------------------------------------------------------------
__global__ __launch_bounds__(256) void qkv_proj_kernel(
    const float* __restrict__ q, const float* __restrict__ k, const float* __restrict__ v,
    const float* __restrict__ Wq, const float* __restrict__ bq,
    const float* __restrict__ Wk, const float* __restrict__ bk,
    const float* __restrict__ Wv, const float* __restrict__ bv,
    unsigned short* __restrict__ Qh, unsigned short* __restrict__ Kh,
    unsigned short* __restrict__ Vt)
{
    __shared__ unsigned short As[128][40];
    __shared__ unsigned short Bs[128][40];

    const int z = blockIdx.z;
    const float* X    = (z == 0) ? q  : (z == 1) ? k  : v;
    const float* W    = (z == 0) ? Wq : (z == 1) ? Wk : Wv;
    const float* bias = (z == 0) ? bq : (z == 1) ? bk : bv;

    const int m0 = blockIdx.y * 128;
    const int n0 = blockIdx.x * 128;
    const int tid = threadIdx.x;
    const int w = tid >> 6, lane = tid & 63, lr = lane & 15, lg = lane >> 4;
    const int wr = w >> 1, wc = w & 1;

    f32x4 acc[4][4];
    #pragma unroll
    for (int mi = 0; mi < 4; ++mi)
        #pragma unroll
        for (int ni = 0; ni < 4; ++ni) acc[mi][ni] = (f32x4){0.f, 0.f, 0.f, 0.f};

    for (int k0 = 0; k0 < 1024; k0 += 32) {
        // stage 128x32 fp32 tiles of X and W -> bf16 LDS (coalesced float4 loads)
        #pragma unroll
        for (int i = 0; i < 4; ++i) {
            int vv = tid + 256 * i;
            int row = vv >> 3, c4 = vv & 7;
            float4 xa = *(const float4*)(X + (size_t)(m0 + row) * 1024 + k0 + c4 * 4);
            float4 xb = *(const float4*)(W + (size_t)(n0 + row) * 1024 + k0 + c4 * 4);
            *(ushort4*)&As[row][c4 * 4] = pack4(xa);
            *(ushort4*)&Bs[row][c4 * 4] = pack4(xb);
        }
        __syncthreads();
        short8 a[4], bf[4];
        #pragma unroll
        for (int mi = 0; mi < 4; ++mi) a[mi]  = *(const short8*)&As[wr * 64 + mi * 16 + lr][lg * 8];
        #pragma unroll
        for (int ni = 0; ni < 4; ++ni) bf[ni] = *(const short8*)&Bs[wc * 64 + ni * 16 + lr][lg * 8];
        #pragma unroll
        for (int mi = 0; mi < 4; ++mi)
            #pragma unroll
            for (int ni = 0; ni < 4; ++ni)
                acc[mi][ni] = MFMA16(a[mi], bf[ni], acc[mi][ni]);
        __syncthreads();
    }

    // epilogue: +bias, convert, store to head-split layouts
    #pragma unroll
    for (int ni = 0; ni < 4; ++ni) {
        int n = n0 + wc * 64 + ni * 16 + lr;
        float bb = bias[n];
        int h = n >> 6, d = n & 63;
        #pragma unroll
        for (int mi = 0; mi < 4; ++mi) {
            #pragma unroll
            for (int r = 0; r < 4; ++r) {
                int m = m0 + wr * 64 + mi * 16 + lg * 4 + r;   // C row = (lane>>4)*4+reg (m89)
                float val = acc[mi][ni][r] + bb;
                int bi = m >> 10, t = m & 1023;
                size_t hb = ((size_t)(bi * 16 + h)) << 16;     // *(1024*64)
                if (z == 0)      Qh[hb + (size_t)t * 64 + d] = f2bf(val);
                else if (z == 1) Kh[hb + (size_t)t * 64 + d] = f2bf(val);
                else             Vt[hb + (size_t)d * 1024 + t] = f2bf(val);
            }
        }
    }
}

// ---------------------------------------------------------------------------
// Kernel 2: attention. One WG = (b,h, 16 q-rows). 4 waves x 256-kpos chunks.
// scores in registers -> softmax (shfl + small LDS) -> write attn (fp32) +
// P (bf16, padded LDS) -> PV via MFMA -> ctx bf16 (B,T,H*D).
// ---------------------------------------------------------------------------
__global__ __launch_bounds__(256) void attn_kernel(
    const unsigned short* __restrict__ Qh, const unsigned short* __restrict__ Kh,
    const unsigned short* __restrict__ Vt, const int* __restrict__ mask,
    float* __restrict__ attn, unsigned short* __restrict__ ctx)
{
    __shared__ unsigned short pb[16][1032];   // P tile bf16, +8 pad -> 2-way worst (free)
    __shared__ float redA[16][4];
    __shared__ float redB[16][4];

    const int qt = blockIdx.x;     // q-tile (0..63)
    const int bh = blockIdx.y;     // b*16+h (0..127)
    const int tid = threadIdx.x;
    const int w = tid >> 6, lane = tid & 63, lr = lane & 15, lg = lane >> 4;
    const int qrow0 = qt * 16;

    // Q fragments (A operand): row=lane&15, k contiguous 8 per lane-group
    const unsigned short* Qbase = Qh + ((size_t)bh << 16) + (size_t)qrow0 * 64;
    short8 aq0 = *(const short8*)(Qbase + (size_t)lr * 64 + lg * 8);
    short8 aq1 = *(const short8*)(Qbase + (size_t)lr * 64 + 32 + lg * 8);

    // scores: wave w covers kpos [256w, 256w+256)
    f32x4 acc[16];
    const unsigned short* Kbase = Kh + ((size_t)bh << 16) + (size_t)(w * 256) * 64;
    #pragma unroll
    for (int nt = 0; nt < 16; ++nt) {
        f32x4 c = {0.f, 0.f, 0.f, 0.f};
        const unsigned short* kp = Kbase + (size_t)(nt * 16 + lr) * 64 + lg * 8;
        short8 b0 = *(const short8*)kp;
        short8 b1 = *(const short8*)(kp + 32);
        c = MFMA16(aq0, b0, c);
        c = MFMA16(aq1, b1, c);
        acc[nt] = c;
    }

    // scale + mask (mask==0 -> -1e9), in registers
    #pragma unroll
    for (int nt = 0; nt < 16; ++nt) {
        int kcol = w * 256 + nt * 16 + lr;
        #pragma unroll
        for (int r = 0; r < 4; ++r) {
            int qr = lg * 4 + r;
            float s = acc[nt][r] * 0.125f;
            int mv = mask[(size_t)(qrow0 + qr) * 1024 + kcol];
            acc[nt][r] = (mv == 0) ? -1.0e9f : s;
        }
    }

    // row max: per-lane over nt, then across the 16 lanes of the group, then across waves
    float pm[4];
    #pragma unroll
    for (int r = 0; r < 4; ++r) {
        float m_ = -3.4e38f;
        #pragma unroll
        for (int nt = 0; nt < 16; ++nt) m_ = fmaxf(m_, acc[nt][r]);
        pm[r] = m_;
    }
    #pragma unroll
    for (int off = 1; off < 16; off <<= 1) {
        #pragma unroll
        for (int r = 0; r < 4; ++r) pm[r] = fmaxf(pm[r], __shfl_xor(pm[r], off));
    }
    if (lr < 4) redA[lg * 4 + lr][w] = pm[lr];
    __syncthreads();
    float rowm[4];
    #pragma unroll
    for (int r = 0; r < 4; ++r)
        rowm[r] = fmaxf(fmaxf(redA[lg * 4 + r][0], redA[lg * 4 + r][1]),
                        fmaxf(redA[lg * 4 + r][2], redA[lg * 4 + r][3]));

    // exp + row sum
    float ps[4] = {0.f, 0.f, 0.f, 0.f};
    #pragma unroll
    for (int nt = 0; nt < 16; ++nt) {
        #pragma unroll
        for (int r = 0; r < 4; ++r) {
            float p = __expf(acc[nt][r] - rowm[r]);
            acc[nt][r] = p;
            ps[r] += p;
        }
    }
    #pragma unroll
    for (int off = 1; off < 16; off <<= 1) {
        #pragma unroll
        for (int r = 0; r < 4; ++r) ps[r] += __shfl_xor(ps[r], off);
    }
    if (lr < 4) redB[lg * 4 + lr][w] = ps[lr];
    __syncthreads();
    float inv[4];
    #pragma unroll
    for (int r = 0; r < 4; ++r) {
        float s = (redB[lg * 4 + r][0] + redB[lg * 4 + r][1]) +
                  (redB[lg * 4 + r][2] + redB[lg * 4 + r][3]);
        inv[r] = 1.0f / s;
    }

    // write attn (coalesced 64B segments) + P bf16 to LDS
    float* arow = attn + ((size_t)bh << 20) + (size_t)qrow0 * 1024;
    #pragma unroll
    for (int nt = 0; nt < 16; ++nt) {
        int kcol = w * 256 + nt * 16 + lr;
        #pragma unroll
        for (int r = 0; r < 4; ++r) {
            int qr = lg * 4 + r;
            float a = acc[nt][r] * inv[r];
            arow[(size_t)qr * 1024 + kcol] = a;
            pb[qr][kcol] = f2bf(a);
        }
    }
    __syncthreads();

    // PV: ctx(16 x 64) = P(16 x 1024) @ V(1024 x 64); wave w -> d cols [16w,16w+16)
    f32x4 co = {0.f, 0.f, 0.f, 0.f};
    const unsigned short* Vbase = Vt + ((size_t)bh << 16) + (size_t)(w * 16) * 1024;
    #pragma unroll 8
    for (int ks = 0; ks < 32; ++ks) {
        short8 ap = *(const short8*)&pb[lr][ks * 32 + lg * 8];
        short8 bv_ = *(const short8*)(Vbase + (size_t)lr * 1024 + ks * 32 + lg * 8);
        co = MFMA16(ap, bv_, co);
    }
    unsigned short* cb = ctx + ((size_t)(bh >> 4) * 1024 + qrow0) * 1024 + (size_t)(bh & 15) * 64;
    #pragma unroll
    for (int r = 0; r < 4; ++r)
        cb[(size_t)(lg * 4 + r) * 1024 + w * 16 + lr] = f2bf(co[r]);
}

// ---------------------------------------------------------------------------
// Kernel 3: out = ctx (8192x1024 bf16) @ Wo.T (1024x64) + bo, fp32 out.
// WG = 64 rows; wave w -> 16 rows x all 64 cols.
// ---------------------------------------------------------------------------
__global__ __launch_bounds__(256) void oproj_kernel(
    const unsigned short* __restrict__ ctx, const float* __restrict__ Wo,
    const float* __restrict__ bo, float* __restrict__ out)
{
    const int m0 = blockIdx.x * 64;
    const int tid = threadIdx.x;
    const int w = tid >> 6, lane = tid & 63, lr = lane & 15, lg = lane >> 4;

    f32x4 acc[4];
    #pragma unroll
    for (int i = 0; i < 4; ++i) acc[i] = (f32x4){0.f, 0.f, 0.f, 0.f};

    const unsigned short* abase = ctx + (size_t)(m0 + w * 16 + lr) * 1024 + lg * 8;
    #pragma unroll 4
    for (int ks = 0; ks < 32; ++ks) {
        short8 a = *(const short8*)(abase + (size_t)ks * 32);
        #pragma unroll
        for (int nt = 0; nt < 4; ++nt) {
            short8 b = cvt8(Wo + (size_t)(nt * 16 + lr) * 1024 + ks * 32 + lg * 8);
            acc[nt] = MFMA16(a, b, acc[nt]);
        }
    }
    #pragma unroll
    for (int nt = 0; nt < 4; ++nt) {
        int n = nt * 16 + lr;
        float bb = bo[n];
        #pragma unroll
        for (int r = 0; r < 4; ++r) {
            int m = m0 + w * 16 + lg * 4 + r;
            out[(size_t)m * 64 + n] = acc[nt][r] + bb;
        }
    }
}

// ---------------------------------------------------------------------------
extern "C" void kernel_launch(void* const* d_in, const int* in_sizes, int n_in,
                              void* d_out, int out_size, void* d_ws, size_t ws_size,
                              hipStream_t stream)
{
    (void)in_sizes; (void)n_in; (void)out_size; (void)ws_size;

    const float* q  = (const float*)d_in[0];
    const float* k  = (const float*)d_in[1];
    const float* v  = (const float*)d_in[2];
    const float* Wq = (const float*)d_in[3];
    const float* bq = (const float*)d_in[4];
    const float* Wk = (const float*)d_in[5];
    const float* bk = (const float*)d_in[6];
    const float* Wv = (const float*)d_in[7];
    const float* bv = (const float*)d_in[8];
    const float* Wo = (const float*)d_in[9];
    const float* bo = (const float*)d_in[10];
    const int* mask = (const int*)d_in[11];

    float* out  = (float*)d_out;
    float* attn = out + (size_t)8 * 1024 * 64;   // tuple order: (out, attn)

    // workspace: 4 x 16 MB bf16 buffers = 64 MB
    unsigned short* Qh  = (unsigned short*)d_ws;
    unsigned short* Kh  = Qh + (size_t)8388608;
    unsigned short* Vt  = Kh + (size_t)8388608;
    unsigned short* ctx = Vt + (size_t)8388608;

    qkv_proj_kernel<<<dim3(8, 64, 3), 256, 0, stream>>>(q, k, v, Wq, bq, Wk, bk, Wv, bv, Qh, Kh, Vt);
    attn_kernel<<<dim3(64, 128), 256, 0, stream>>>(Qh, Kh, Vt, mask, attn, ctx);
    oproj_kernel<<<dim3(128), 256, 0, stream>>>(ctx, Wo, bo, out);
}